// Round 4
// baseline (453.767 us; speedup 1.0000x reference)
//
#include <hip/hip_runtime.h>
#include <math.h>

typedef __attribute__((ext_vector_type(8))) short short8;
typedef __attribute__((ext_vector_type(4))) float floatx4;

#define EPS 1e-12f

// ws layout (u16 element offsets unless noted)
#define WS_AMAIN 0        // [400][128] rows: 0-127 W1se3, 128-255 W2se3, 256-383 vsdir,
                          //            384-399 zero except 386 = ones/128
#define WS_ASCAL 51200    // [256][128] rows: 0-127 sv_W, 128-255 ss_W
#define WS_AFC   83968    // [128][256] crossfc_se3 (k: 0-127 pairs with cr, 128-255 with v2)
#define WS_AVS   116736   // [128][128] vs_W
#define WS_VDR_B 266240   // byte offset: fp32[128] rowsum(vsdir)

__device__ __forceinline__ unsigned short f2bf(float f) {
  union { float f; unsigned u; } v; v.f = f;
  unsigned r = v.u + 0x7FFFu + ((v.u >> 16) & 1u);
  return (unsigned short)(r >> 16);
}
__device__ __forceinline__ float bf2f(unsigned u16) {
  union { unsigned u; float f; } v; v.u = u16 << 16;
  return v.f;
}
// HW packed f32->bf16 (RNE via MODE.round default): 1 VALU op per 2 elements.
__device__ __forceinline__ unsigned pk2bf(float lo, float hi) {
  unsigned r;
  asm("v_cvt_pk_bf16_f32 %0, %1, %2" : "=v"(r) : "v"(lo), "v"(hi));
  return r;
}

__device__ __forceinline__ float block_sum_256(float v, float* red) {
  const int t = threadIdx.x;
  red[t] = v;
  __syncthreads();
  for (int s = 128; s > 0; s >>= 1) {
    if (t < s) red[t] += red[t + s];
    __syncthreads();
  }
  float r = red[0];
  __syncthreads();
  return r;
}

__global__ __launch_bounds__(256) void k_pre(
    const float* __restrict__ weight, const float* __restrict__ sv_W,
    const float* __restrict__ cross_w, const float* __restrict__ crossfc_w,
    const float* __restrict__ vsdir_w, const float* __restrict__ vs_W,
    const float* __restrict__ ss_W, unsigned short* __restrict__ wsu,
    float* __restrict__ vdr) {
  __shared__ float red[256];
  const int o = blockIdx.x;   // 128 blocks, one per output row
  const int t = threadIdx.x;  // 256

  float s1 = block_sum_256((t < 127) ? weight[o * 127 + t] : 0.f, red);
  if (t < 128)
    wsu[WS_AMAIN + o * 128 + t] = f2bf((t < 127) ? weight[o * 127 + t] : 1.f - s1);

  float s2 = block_sum_256((t < 127) ? cross_w[o * 127 + t] : 0.f, red);
  if (t < 128)
    wsu[WS_AMAIN + (128 + o) * 128 + t] = f2bf((t < 127) ? cross_w[o * 127 + t] : 1.f - s2);

  float s4 = block_sum_256((t < 128) ? vsdir_w[o * 128 + t] : 0.f, red);
  if (t < 128)
    wsu[WS_AMAIN + (256 + o) * 128 + t] = f2bf(vsdir_w[o * 128 + t]);
  if (t == 0) vdr[o] = s4;

  float s3 = block_sum_256((t < 255) ? crossfc_w[o * 255 + t] : 0.f, red);
  wsu[WS_AFC + o * 256 + t] = f2bf((t < 255) ? crossfc_w[o * 255 + t] : 1.f - s3);

  if (t < 128) {
    wsu[WS_ASCAL + o * 128 + t]         = f2bf(sv_W[o * 128 + t]);
    wsu[WS_ASCAL + (128 + o) * 128 + t] = f2bf(ss_W[o * 128 + t]);
    wsu[WS_AVS + o * 128 + t]           = f2bf(vs_W[o * 128 + t]);
  }
  if (o == 0) {
    for (int l = t; l < 16 * 128; l += 256) wsu[WS_AMAIN + 384 * 128 + l] = 0;
    if (t < 128) wsu[WS_AMAIN + 386 * 128 + t] = f2bf(1.f / 128.f);
  }
}

// Fused MFMA kernel. 16-column N-tile, 512 threads = 8 waves (8 rg x 16 rows),
// LDS ~36.6 KB -> 4 blocks/CU = 32 waves/CU (100% wave slots). Wave rg owns
// output rows [rg*16, rg*16+16) over all 16 tile columns. Channel reductions
// go through xred[12 slots] with >=1 full barrier between a slot's read and
// its reuse-write. 6 barriers total (v2m and csum algebraically fused).
__global__ __launch_bounds__(512, 8) void k_main(
    const float* __restrict__ v_in, const float* __restrict__ s_in,
    const unsigned short* __restrict__ wsu, const float* __restrict__ vdr,
    const float* __restrict__ sv_b, const float* __restrict__ vs_b,
    const float* __restrict__ ss_b,
    float* __restrict__ v_out, float* __restrict__ s_out) {
  const int t = threadIdx.x;
  const int wave = t >> 6, lane = t & 63;
  const int q = lane >> 4, ln = lane & 15;
  const int rg = wave;            // row group: output rows rg*16..rg*16+15
  const int rb = rg * 16;
  // XCD-aware bijective swizzle (4096 blocks = 8 XCD x 512): consecutive
  // logical tiles (sharing v_in cache lines + weight panels) stay on one XCD.
  const int bid = (int)(blockIdx.x & 7) * 512 + (int)(blockIdx.x >> 3);
  const int b = bid >> 8;
  const int n0 = (bid & 255) * 16;

  __shared__ __align__(16) unsigned short xB[48 * 136];   // x; later cr
  __shared__ __align__(16) unsigned short v2B[48 * 136];  // v2
  __shared__ __align__(16) unsigned short sB[16 * 136];   // s; later sfn
  __shared__ float xred[12][8][16];  // cross-rowgroup reduction scratch

  // ---- staging: global fp32 -> bf16 LDS in B layout [n][k] ----
  {
    const float* vb = v_in + (size_t)b * (128 * 3 * 4096) + n0;
    for (int l = t; l < 1536; l += 512) {   // 3 iters/thread
      const int c = l / 12, rr = l % 12;
      const int v = rr >> 2, j4 = (rr & 3) * 4;
      const float4 f = *(const float4*)(vb + (size_t)(c * 3 + v) * 4096 + j4);
      const int base = (v * 16 + j4) * 136 + c;
      const unsigned p01 = pk2bf(f.x, f.y);
      const unsigned p23 = pk2bf(f.z, f.w);
      xB[base]       = (unsigned short)p01;
      xB[base + 136] = (unsigned short)(p01 >> 16);
      xB[base + 272] = (unsigned short)p23;
      xB[base + 408] = (unsigned short)(p23 >> 16);
    }
    const float* sb = s_in + (size_t)b * (128 * 4096) + n0;
    {                                       // 1 iter/thread
      const int c = t >> 2, j4 = (t & 3) * 4;
      const float4 f = *(const float4*)(sb + (size_t)c * 4096 + j4);
      const int base = j4 * 136 + c;
      const unsigned p01 = pk2bf(f.x, f.y);
      const unsigned p23 = pk2bf(f.z, f.w);
      sB[base]       = (unsigned short)p01;
      sB[base + 136] = (unsigned short)(p01 >> 16);
      sB[base + 272] = (unsigned short)p23;
      sB[base + 408] = (unsigned short)(p23 >> 16);
    }
  }
  __syncthreads();  // B1

  // ---- g0: sv/ss GEMM (A_scal rows rb..rb+15 and 128+rb..128+rb+15) ----
  floatx4 accS[2];
  accS[0] = (floatx4){0.f, 0.f, 0.f, 0.f};
  accS[1] = (floatx4){0.f, 0.f, 0.f, 0.f};
#pragma unroll
  for (int k = 0; k < 4; ++k) {
    const short8 bf = *(const short8*)(sB + ln * 136 + k * 32 + q * 8);
    const unsigned short* ap = wsu + WS_ASCAL + (rb + ln) * 128 + k * 32 + q * 8;
    accS[0] = __builtin_amdgcn_mfma_f32_16x16x32_bf16(
        *(const short8*)ap, bf, accS[0], 0, 0, 0);
    accS[1] = __builtin_amdgcn_mfma_f32_16x16x32_bf16(
        *(const short8*)(ap + 128 * 128), bf, accS[1], 0, 0, 0);
  }
  float s2v[4], tssb[4];
  {
    float nrm = 0.f;
    const float4 bb = *(const float4*)(sv_b + rb + q * 4);
    const float* bp = (const float*)&bb;
#pragma unroll
    for (int r = 0; r < 4; ++r) {
      const float tv = accS[0][r] + bp[r];
      s2v[r] = tv;
      nrm += tv * tv;
    }
    nrm += __shfl_xor(nrm, 16);
    nrm += __shfl_xor(nrm, 32);
    if (lane < 16) xred[0][rg][ln] = nrm;
    __syncthreads();  // B2
    float ntot = 0.f;
#pragma unroll
    for (int g = 0; g < 8; ++g) ntot += xred[0][g][ln];
    const float inv = 1.f / fmaxf(sqrtf(ntot), EPS);
#pragma unroll
    for (int r = 0; r < 4; ++r) s2v[r] *= inv;
    const float4 b1 = *(const float4*)(ss_b + rb + q * 4);
    const float4 b2 = *(const float4*)(vs_b + rb + q * 4);
    const float* p1 = (const float*)&b1;
    const float* p2 = (const float*)&b2;
#pragma unroll
    for (int r = 0; r < 4; ++r) tssb[r] = accS[1][r] + p1[r] + p2[r];
  }

  // ---- g1: dd (vsdir rows rb..rb+15) + means tile (row 386 = ones/128) ----
  floatx4 accD[2][3];
#pragma unroll
  for (int i = 0; i < 2; ++i)
#pragma unroll
    for (int v = 0; v < 3; ++v) accD[i][v] = (floatx4){0.f, 0.f, 0.f, 0.f};
#pragma unroll
  for (int k = 0; k < 4; ++k) {
    short8 bfv[3];
#pragma unroll
    for (int v = 0; v < 3; ++v)
      bfv[v] = *(const short8*)(xB + (v * 16 + ln) * 136 + k * 32 + q * 8);
    const unsigned short* ap = wsu + WS_AMAIN + (256 + rb + ln) * 128 + k * 32 + q * 8;
    const short8 a0 = *(const short8*)ap;
    const unsigned short* am = wsu + WS_AMAIN + (384 + ln) * 128 + k * 32 + q * 8;
    const short8 a1 = *(const short8*)am;
#pragma unroll
    for (int v = 0; v < 3; ++v) {
      accD[0][v] = __builtin_amdgcn_mfma_f32_16x16x32_bf16(a0, bfv[v], accD[0][v], 0, 0, 0);
      accD[1][v] = __builtin_amdgcn_mfma_f32_16x16x32_bf16(a1, bfv[v], accD[1][v], 0, 0, 0);
    }
  }
  float xm[3];
#pragma unroll
  for (int v = 0; v < 3; ++v) xm[v] = __shfl(accD[1][v][2], ln);  // row 386

  // ---- scalar path: sfv -> sfn -> LDS (over sB, own k-range) ----
  {
    float sfv[4];
    float ssum = 0.f;
    const float4 rs4 = *(const float4*)(vdr + rb + q * 4);
    const float* rp = (const float*)&rs4;
    uint2 pk[3];
#pragma unroll
    for (int v = 0; v < 3; ++v)
      pk[v] = *(const uint2*)(xB + (v * 16 + ln) * 136 + rb + q * 4);
#pragma unroll
    for (int r = 0; r < 4; ++r) {
      float d[3], xr[3];
#pragma unroll
      for (int v = 0; v < 3; ++v) {
        d[v] = accD[0][v][r] - rp[r] * xm[v];
        const unsigned w = (r < 2) ? pk[v].x : pk[v].y;
        xr[v] = bf2f((w >> ((r & 1) * 16)) & 0xffffu) - xm[v];
      }
      const float n2 = d[0] * d[0] + d[1] * d[1] + d[2] * d[2];
      const float dinv = 1.f / fmaxf(sqrtf(n2), EPS);
      const float sv_ = (xr[0] * d[0] + xr[1] * d[1] + xr[2] * d[2]) * dinv;
      sfv[r] = sv_;
      ssum += sv_ * sv_;
    }
    ssum += __shfl_xor(ssum, 16);
    ssum += __shfl_xor(ssum, 32);
    if (lane < 16) xred[1][rg][ln] = ssum;
    __syncthreads();  // B3
    float stot = 0.f;
#pragma unroll
    for (int g = 0; g < 8; ++g) stot += xred[1][g][ln];
    const float sinv = 1.f / fmaxf(sqrtf(stot), EPS);
    const unsigned lo = pk2bf(sfv[0] * sinv, sfv[1] * sinv);
    const unsigned hi = pk2bf(sfv[2] * sinv, sfv[3] * sinv);
    *(uint2*)(sB + ln * 136 + rb + q * 4) = make_uint2(lo, hi);
  }

  // ---- g2a: v1 = W1se3@x (rows rb..rb+15); fused vmn/v2m sums; write v2B ----
  floatx4 accV[3];
#pragma unroll
  for (int v = 0; v < 3; ++v) accV[v] = (floatx4){0.f, 0.f, 0.f, 0.f};
#pragma unroll
  for (int k = 0; k < 4; ++k) {
    short8 bfv[3];
#pragma unroll
    for (int v = 0; v < 3; ++v)
      bfv[v] = *(const short8*)(xB + (v * 16 + ln) * 136 + k * 32 + q * 8);
    const unsigned short* ap = wsu + WS_AMAIN + (rb + ln) * 128 + k * 32 + q * 8;
    const short8 a = *(const short8*)ap;
#pragma unroll
    for (int v = 0; v < 3; ++v)
      accV[v] = __builtin_amdgcn_mfma_f32_16x16x32_bf16(a, bfv[v], accV[v], 0, 0, 0);
  }
  // pre-barrier sums: sa = sum(v1), sb = sum(s2v*v1), sc = sum(s2v)
#pragma unroll
  for (int v = 0; v < 3; ++v) {
    float sa = 0.f, sb2 = 0.f;
#pragma unroll
    for (int r = 0; r < 4; ++r) {
      sa += accV[v][r];
      sb2 += s2v[r] * accV[v][r];
    }
    sa += __shfl_xor(sa, 16);   sa += __shfl_xor(sa, 32);
    sb2 += __shfl_xor(sb2, 16); sb2 += __shfl_xor(sb2, 32);
    if (lane < 16) { xred[2 + v][rg][ln] = sa; xred[5 + v][rg][ln] = sb2; }
  }
  {
    float sc = s2v[0] + s2v[1] + s2v[2] + s2v[3];
    sc += __shfl_xor(sc, 16);
    sc += __shfl_xor(sc, 32);
    if (lane < 16) xred[8][rg][ln] = sc;
  }
  __syncthreads();  // B4
  float vmn[3], v2m[3];
  {
    float sct = 0.f;
#pragma unroll
    for (int g = 0; g < 8; ++g) sct += xred[8][g][ln];
#pragma unroll
    for (int v = 0; v < 3; ++v) {
      float sat = 0.f, sbt = 0.f;
#pragma unroll
      for (int g = 0; g < 8; ++g) { sat += xred[2 + v][g][ln]; sbt += xred[5 + v][g][ln]; }
      vmn[v] = sat * (1.f / 128.f);
      // mean(v2) = [sum(s2v*v1) + vmn*(128 - sum(s2v))] / 128
      v2m[v] = (sbt + vmn[v] * (128.f - sct)) * (1.f / 128.f);
    }
  }
#pragma unroll
  for (int v = 0; v < 3; ++v) {
#pragma unroll
    for (int r = 0; r < 4; ++r)
      accV[v][r] = (accV[v][r] - vmn[v]) * s2v[r] + vmn[v];
    const unsigned lo = pk2bf(accV[v][0], accV[v][1]);
    const unsigned hi = pk2bf(accV[v][2], accV[v][3]);
    *(uint2*)(v2B + (v * 16 + ln) * 136 + rb + q * 4) = make_uint2(lo, hi);
  }

  // ---- g2b: vd = W2se3@x (rows rb..rb+15); dmn + |vd|^2 sums; cr over xB ----
  floatx4 accW[3];
#pragma unroll
  for (int v = 0; v < 3; ++v) accW[v] = (floatx4){0.f, 0.f, 0.f, 0.f};
#pragma unroll
  for (int k = 0; k < 4; ++k) {
    short8 bfv[3];
#pragma unroll
    for (int v = 0; v < 3; ++v)
      bfv[v] = *(const short8*)(xB + (v * 16 + ln) * 136 + k * 32 + q * 8);
    const unsigned short* ap = wsu + WS_AMAIN + (128 + rb + ln) * 128 + k * 32 + q * 8;
    const short8 a = *(const short8*)ap;
#pragma unroll
    for (int v = 0; v < 3; ++v)
      accW[v] = __builtin_amdgcn_mfma_f32_16x16x32_bf16(a, bfv[v], accW[v], 0, 0, 0);
  }
  {
    float ssq = 0.f;
#pragma unroll
    for (int v = 0; v < 3; ++v) {
      float s = 0.f;
#pragma unroll
      for (int r = 0; r < 4; ++r) {
        s += accW[v][r];
        ssq += accW[v][r] * accW[v][r];
      }
      s += __shfl_xor(s, 16);
      s += __shfl_xor(s, 32);
      if (lane < 16) xred[9 + v][rg][ln] = s;
    }
    ssq += __shfl_xor(ssq, 16);
    ssq += __shfl_xor(ssq, 32);
    if (lane < 16) xred[0][rg][ln] = ssq;  // reuse slot 0 (read ended pre-B3)
  }
  __syncthreads();  // B5 (also: all waves' x-reads of xB are complete)
  float dmn[3];
  {
#pragma unroll
    for (int v = 0; v < 3; ++v) {
      float s = 0.f;
#pragma unroll
      for (int g = 0; g < 8; ++g) s += xred[9 + v][g][ln];
      dmn[v] = s * (1.f / 128.f);
    }
  }
  {
    float sqt = 0.f;
#pragma unroll
    for (int g = 0; g < 8; ++g) sqt += xred[0][g][ln];
    // sum |vd - dmn|^2 = sum|vd|^2 - 128*|dmn|^2
    const float ctot = sqt - 128.f * (dmn[0] * dmn[0] + dmn[1] * dmn[1] + dmn[2] * dmn[2]);
    const float cninv = 1.f / fmaxf(sqrtf(ctot), EPS);
    float crv[3][4];
#pragma unroll
    for (int r = 0; r < 4; ++r) {
      const float a0 = accW[0][r] - dmn[0];
      const float a1 = accW[1][r] - dmn[1];
      const float a2 = accW[2][r] - dmn[2];
      const float an = sqrtf(a0 * a0 + a1 * a1 + a2 * a2);
      const float sc = an / fmaxf(an, EPS) * cninv;
      const float h0 = a0 * sc, h1 = a1 * sc, h2 = a2 * sc;
      const float w0 = accV[0][r], w1 = accV[1][r], w2 = accV[2][r];
      const float g0 = w0 - v2m[0], g1 = w1 - v2m[1], g2 = w2 - v2m[2];
      crv[0][r] = h1 * g2 - h2 * g1 + w0;
      crv[1][r] = h2 * g0 - h0 * g2 + w1;
      crv[2][r] = h0 * g1 - h1 * g0 + w2;
    }
#pragma unroll
    for (int v = 0; v < 3; ++v) {
      const unsigned lo = pk2bf(crv[v][0], crv[v][1]);
      const unsigned hi = pk2bf(crv[v][2], crv[v][3]);
      *(uint2*)(xB + (v * 16 + ln) * 136 + rb + q * 4) = make_uint2(lo, hi);
    }
  }
  __syncthreads();  // B6: cr/v2/sfn complete -> g3 may read full K

  // ---- g3: crossfc (K=256 over [cr;v2]) + vs (K=128 over sfn) GEMMs ----
  floatx4 accO[3];
  floatx4 accP = (floatx4){0.f, 0.f, 0.f, 0.f};
#pragma unroll
  for (int v = 0; v < 3; ++v) accO[v] = (floatx4){0.f, 0.f, 0.f, 0.f};
#pragma unroll
  for (int ks = 0; ks < 8; ++ks) {
    const unsigned short* src = (ks < 4) ? xB : v2B;
    const int kk = ks & 3;
    short8 bfv[3];
#pragma unroll
    for (int v = 0; v < 3; ++v)
      bfv[v] = *(const short8*)(src + (v * 16 + ln) * 136 + kk * 32 + q * 8);
    const unsigned short* afc = wsu + WS_AFC + (rb + ln) * 256 + ks * 32 + q * 8;
    const short8 a = *(const short8*)afc;
#pragma unroll
    for (int v = 0; v < 3; ++v)
      accO[v] = __builtin_amdgcn_mfma_f32_16x16x32_bf16(a, bfv[v], accO[v], 0, 0, 0);
    if (ks < 4) {
      const short8 bfs = *(const short8*)(sB + ln * 136 + kk * 32 + q * 8);
      const unsigned short* avs = wsu + WS_AVS + (rb + ln) * 128 + kk * 32 + q * 8;
      accP = __builtin_amdgcn_mfma_f32_16x16x32_bf16(
          *(const short8*)(avs), bfs, accP, 0, 0, 0);
    }
  }

  // ---- epilogue stores (rows rb..rb+15) ----
  const int gc = n0 + ln;
  float* vob = v_out + (size_t)b * (128 * 3 * 4096) + gc;
  float* sob = s_out + (size_t)b * (128 * 4096) + gc;
#pragma unroll
  for (int r = 0; r < 4; ++r) {
    const int o = rb + q * 4 + r;
#pragma unroll
    for (int v = 0; v < 3; ++v)
      vob[(size_t)(o * 3 + v) * 4096] = accO[v][r];
    sob[(size_t)o * 4096] = accP[r] + tssb[r];
  }
}

extern "C" void kernel_launch(void* const* d_in, const int* in_sizes, int n_in,
                              void* d_out, int out_size, void* d_ws, size_t ws_size,
                              hipStream_t stream) {
  const float* v_in      = (const float*)d_in[0];
  const float* s_in      = (const float*)d_in[1];
  const float* weight    = (const float*)d_in[2];
  const float* sv_W      = (const float*)d_in[3];
  const float* sv_b      = (const float*)d_in[4];
  const float* cross_w   = (const float*)d_in[5];
  const float* crossfc_w = (const float*)d_in[6];
  const float* vsdir_w   = (const float*)d_in[7];
  const float* vs_W      = (const float*)d_in[8];
  const float* vs_b      = (const float*)d_in[9];
  const float* ss_W      = (const float*)d_in[10];
  const float* ss_b      = (const float*)d_in[11];

  float* out = (float*)d_out;
  float* v_out = out;                                  // [16][128][3][4096]
  float* s_out = out + (size_t)16 * 128 * 3 * 4096;    // [16][128][4096]
  unsigned short* wsu = (unsigned short*)d_ws;
  float* vdr = (float*)((char*)d_ws + WS_VDR_B);

  hipLaunchKernelGGL(k_pre, dim3(128), dim3(256), 0, stream,
                     weight, sv_W, cross_w, crossfc_w, vsdir_w, vs_W, ss_W, wsu, vdr);
  hipLaunchKernelGGL(k_main, dim3(4096), dim3(512), 0, stream,
                     v_in, s_in, wsu, vdr, sv_b, vs_b, ss_b, v_out, s_out);
}